// Round 12
// baseline (402.840 us; speedup 1.0000x reference)
//
#include <hip/hip_runtime.h>

// B=8, NQ=1024, NC=4096, D=256, C+1=25. FP32 I/O; labels int32.
// R20 (resubmit — R11-round bench was a GPU-acquisition timeout, never ran):
// attn de-LDS'd on the QK side. sA deleted — QK A-fragments are
// 16B/lane coalesced reads of the L2-resident c-slice, 2-deep pipelined
// from GLOBAL (bit-identical data to the old sA path). LDS 69->37.25KB
// (sB dbuf + Pw) -> occupancy 2->3 blocks/CU (12 waves, was 8): attn was
// latency-bound (no pipe >50%, occ 20%). ns=8 (grid 1024, R10-PROVEN
// decode b=u/sp=xcd, FETCH 33MB anchor) so the grid can fill 3+/CU.
// Issue order per iter: QK global loads (+next-tile ks0 preload) -> ml
// loads -> fence -> sB DMA -> softmax (vmcnt leaves DMA in flight) ->
// PV (lgkm only) -> barrier drains DMA with a full phase of slack.
// emb/final/wprep unchanged from R19 (async-DMA emb; sB slot swizzle kept).

typedef __attribute__((ext_vector_type(8))) _Float16 half8;
typedef __attribute__((ext_vector_type(4))) float floatx4;

#define WB 8
#define WNQ 1024
#define WNC 4096
#define NROWS 8192          // B*NQ

static __device__ __forceinline__ float logsig(float x) {
    return (x >= 0.f) ? -log1pf(__expf(-x)) : x - log1pf(__expf(x));
}

union V16h { int4 v; half8 h8; _Float16 h[8]; unsigned short s[8]; uint2 u2[2]; };
union F8   { float4 v[2]; float f[8]; };
union H4   { _Float16 h[4]; uint2 u; unsigned short s[4]; };

static __device__ __forceinline__ void async_lds16(const _Float16* g, _Float16* l) {
    __builtin_amdgcn_global_load_lds(
        (const __attribute__((address_space(1))) unsigned int*)g,
        (__attribute__((address_space(3))) unsigned int*)l,
        16, 0, 0);
}

static __device__ __forceinline__ void async_lds16f(const float* g, float* l) {
    __builtin_amdgcn_global_load_lds(
        (const __attribute__((address_space(1))) unsigned int*)g,
        (__attribute__((address_space(3))) unsigned int*)l,
        16, 0, 0);
}

// ---------------------------------------------------------------------------
// wprep: WT fp16 [256 n][512 k] = W_rel^T; GenB fp16 [32 n][256 k].
// ---------------------------------------------------------------------------
__global__ void wprep_kernel(const float* __restrict__ Wrel,
                             const float* __restrict__ Wgen,
                             const float* __restrict__ Wcp,
                             _Float16* __restrict__ WT,
                             _Float16* __restrict__ GenB)
{
    const int bx = blockIdx.x;
    if (bx < 256) {
        const int n = bx;
        for (int k = threadIdx.x; k < 512; k += 256)
            WT[(long)n * 512 + k] = (_Float16)Wrel[(long)k * 256 + n];
    } else {
        const int n = bx - 256;
        const int k = threadIdx.x;
        float v = 0.f;
        if (n < 25)       v = Wgen[(long)k * 25 + n];
        else if (n == 25) v = Wcp[k];
        GenB[(long)n * 256 + k] = (_Float16)v;
    }
}

// ---------------------------------------------------------------------------
// emb v3 (R18/R19): concat(head,tail) @ W_rel + b_rel -> fp16. fp32 A-tile
// async-DMA'd to LDS, double-buffered, single barrier per K-step.
// ---------------------------------------------------------------------------
__global__ __launch_bounds__(256, 2) void emb_kernel(
    const float* __restrict__ q_head, const float* __restrict__ q_tail,
    const float* __restrict__ c_head, const float* __restrict__ c_tail,
    const _Float16* __restrict__ WT,
    const float* __restrict__ brel,
    const _Float16* __restrict__ GenB,
    const float* __restrict__ bgen,
    _Float16* __restrict__ Qf, _Float16* __restrict__ Cf,
    _Float16* __restrict__ CfT,
    float* __restrict__ genlog)
{
    __shared__ float sA32[2][2048];    // 16 KB dbuf fp32 A-tile [64r][32k] chunk-swizzled
    __shared__ _Float16 sO[64 * 264];  // 33 KB: q natural [m][264] / c swizzled

    const int tid  = threadIdx.x;
    const int lane = tid & 63;
    const int wv   = tid >> 6;
    const int l15  = lane & 15;
    const int quad = lane >> 4;
    const int n0   = wv * 64;

    const float* head; const float* tail; _Float16* Ef;
    long m0; bool isQ;
    if (blockIdx.x < 128) {
        isQ = true;  head = q_head; tail = q_tail; Ef = Qf;
        m0 = (long)blockIdx.x * 64;
    } else {
        isQ = false; head = c_head; tail = c_tail; Ef = Cf;
        m0 = (long)(blockIdx.x - 128) * 64;
    }

    const int srow = wv * 8 + (lane >> 3);   // row within 32-row half-tile
    const int sch  = lane & 7;               // physical chunk slot

    auto stageA = [&](int kg, int buf) {
        const float* srcb = (kg < 256) ? (head + kg) : (tail + (kg - 256));
#pragma unroll
        for (int t = 0; t < 2; ++t) {
            const int r = t * 32 + srow;                       // tile row 0..63
            const int colsw = ((sch ^ (r & 7)) << 2);          // swizzled chunk *4 floats
            async_lds16f(srcb + (m0 + r) * 256 + colsw,
                         &sA32[buf][t * 1024 + wv * 256]);     // wave-uniform base
        }
    };

    floatx4 acc[4][4];
#pragma unroll
    for (int a = 0; a < 4; ++a)
#pragma unroll
        for (int bq = 0; bq < 4; ++bq) acc[a][bq] = (floatx4)(0.0f);

    V16h wCur[4];
#pragma unroll
    for (int nt = 0; nt < 4; ++nt)
        wCur[nt].v = *(const int4*)(WT + (long)(n0 + nt * 16 + l15) * 512 + quad * 8);

    stageA(0, 0);                       // prologue prefetch into buf 0

    for (int ks = 0; ks < 16; ++ks) {
        const int cur = ks & 1;
        __syncthreads();                // drains own DMA (issued last iter) + readers

        V16h wNxt[4];
        if (ks < 15) {
            const int kg = (ks + 1) * 32;
            stageA(kg, cur ^ 1);
#pragma unroll
            for (int nt = 0; nt < 4; ++nt)
                wNxt[nt].v = *(const int4*)(WT + (long)(n0 + nt * 16 + l15) * 512 + kg + quad * 8);
        } else {
#pragma unroll
            for (int nt = 0; nt < 4; ++nt) wNxt[nt] = wCur[nt];
        }

        V16h af[4];
#pragma unroll
        for (int mb = 0; mb < 4; ++mb) {
            const int row  = mb * 16 + l15;
            const int base = row * 32;
            const int p0   = ((quad * 2)     ^ (row & 7)) * 4;
            const int p1   = ((quad * 2 + 1) ^ (row & 7)) * 4;
            const float4 f0 = *(const float4*)&sA32[cur][base + p0];
            const float4 f1 = *(const float4*)&sA32[cur][base + p1];
            af[mb].h[0] = (_Float16)f0.x; af[mb].h[1] = (_Float16)f0.y;
            af[mb].h[2] = (_Float16)f0.z; af[mb].h[3] = (_Float16)f0.w;
            af[mb].h[4] = (_Float16)f1.x; af[mb].h[5] = (_Float16)f1.y;
            af[mb].h[6] = (_Float16)f1.z; af[mb].h[7] = (_Float16)f1.w;
        }
#pragma unroll
        for (int mb = 0; mb < 4; ++mb)
#pragma unroll
            for (int nt = 0; nt < 4; ++nt)
                acc[mb][nt] = __builtin_amdgcn_mfma_f32_16x16x32_f16(af[mb].h8, wCur[nt].h8, acc[mb][nt], 0, 0, 0);

#pragma unroll
        for (int nt = 0; nt < 4; ++nt) wCur[nt] = wNxt[nt];
    }

    float bias[4];
#pragma unroll
    for (int nt = 0; nt < 4; ++nt) bias[nt] = brel[n0 + nt * 16 + l15];

#pragma unroll
    for (int mb = 0; mb < 4; ++mb)
#pragma unroll
        for (int nt = 0; nt < 4; ++nt) {
            H4 hq;
#pragma unroll
            for (int r = 0; r < 4; ++r) {
                const long row = m0 + mb * 16 + quad * 4 + r;
                const _Float16 h = (_Float16)(acc[mb][nt][r] + bias[nt]);
                Ef[row * 256 + n0 + nt * 16 + l15] = h;
                hq.h[r] = h;
                if (isQ)   // natural tile for fused gen head
                    sO[(mb * 16 + quad * 4 + r) * 264 + n0 + nt * 16 + l15] = h;
            }
            if (!isQ) {
                const int n  = n0 + nt * 16 + l15;
                const int sw = (mb * 4 + quad) ^ l15;
                *(uint2*)&sO[n * 64 + sw * 4] = hq.u;
            }
        }

    __syncthreads();
    if (isQ) {
        // ---- fused gen head: genlog[m][32] = q_emb @ GenB^T (+bgen) ----
        floatx4 ga[2];
        ga[0] = (floatx4)(0.0f); ga[1] = (floatx4)(0.0f);
#pragma unroll
        for (int ks = 0; ks < 8; ++ks) {
            V16h a, b0, b1;
            a.v  = *(const int4*)&sO[(wv * 16 + l15) * 264 + ks * 32 + quad * 8];
            b0.v = *(const int4*)(GenB + (long)(l15)      * 256 + ks * 32 + quad * 8);
            b1.v = *(const int4*)(GenB + (long)(16 + l15) * 256 + ks * 32 + quad * 8);
            ga[0] = __builtin_amdgcn_mfma_f32_16x16x32_f16(a.h8, b0.h8, ga[0], 0, 0, 0);
            ga[1] = __builtin_amdgcn_mfma_f32_16x16x32_f16(a.h8, b1.h8, ga[1], 0, 0, 0);
        }
#pragma unroll
        for (int nt = 0; nt < 2; ++nt) {
            const int col = nt * 16 + l15;
            const float bb = (col < 25) ? bgen[col] : 0.f;
#pragma unroll
            for (int r = 0; r < 4; ++r)
                genlog[(m0 + wv * 16 + quad * 4 + r) * 32 + col] = ga[nt][r] + bb;
        }
    } else {
        const int bidx = (int)(m0 >> 12);
        const int jc0  = (int)(m0 & 4095);
        const int c    = tid & 7;
        const int nl   = tid >> 3;
#pragma unroll
        for (int i = 0; i < 8; ++i) {
            const int n  = nl + 32 * i;
            const int s0 = (2 * c)     ^ (n & 15);
            const int s1 = (2 * c + 1) ^ (n & 15);
            const uint2 u0 = *(const uint2*)&sO[n * 64 + s0 * 4];
            const uint2 u1 = *(const uint2*)&sO[n * 64 + s1 * 4];
            int4 out; out.x = u0.x; out.y = u0.y; out.z = u1.x; out.w = u1.y;
            *(int4*)&CfT[(long)bidx * 1048576 + (long)n * 4096 + jc0 + c * 8] = out;
        }
    }
}

// ---------------------------------------------------------------------------
// Fused flash attention + grouped class sums. 256 thr, q-tile 64, j-tile 32.
// grid 16qt*8b*8ns = 1024 (R10-proven decode: b=u, sp=xcd). LDS 37.25KB
// (sB dbuf + Pw; sA DELETED — QK A-frags read 16B/lane coalesced from the
// L2-resident c slice, 2-deep pipelined). 3 blocks/CU target.
// l via ones-column MFMA (B col 31 == 1 -> O[17] accumulates row sums).
// ---------------------------------------------------------------------------
__global__ __launch_bounds__(256, 3) void attn_kernel(
    const _Float16* __restrict__ qf,
    const _Float16* __restrict__ cf,
    const _Float16* __restrict__ cfT,
    const int*      __restrict__ labels,
    const float*    __restrict__ maskp,
    unsigned short* __restrict__ Oh,    // fp16 [ns*8192][288]
    float* __restrict__ Mst,
    float* __restrict__ Lst,
    int jtiles, int nsh)
{
    __shared__ _Float16 sB[2][8192];    // 32 KB dbuf transposed c tile (slot-swizzled)
    __shared__ _Float16 Pw[4][16 * 40]; //  5 KB per-wave P

    const int tid  = threadIdx.x;
    const int lane = tid & 63;
    const int wv   = tid >> 6;
    const int l15  = lane & 15;
    const int quad = lane >> 4;

    const int f   = blockIdx.x;
    const int xcd = f & 7;
    const int seq = f >> 3;
    const int qt  = seq & 15;
    const int u   = seq >> 4;
    const int pr  = u * 8 + xcd;
    const int b   = pr >> nsh;
    const int sp  = pr & ((1 << nsh) - 1);
    const int q0  = qt * 64;

    V16h qfr[8];
    {
        const long qrow = (long)b * WNQ + q0 + wv * 16 + l15;
#pragma unroll
        for (int ks = 0; ks < 8; ++ks)
            qfr[ks].v = *(const int4*)(qf + qrow * 256 + ks * 32 + quad * 8);
    }

    floatx4 O[18];
#pragma unroll
    for (int i = 0; i < 18; ++i) O[i] = (floatx4)(0.0f);
    float m_run = -INFINITY;

    const int jb0 = sp * (jtiles * 32);
    const long cb0 = ((long)b * WNC + jb0) * 256;

    // per-lane QK A-fragment offsets within a 32-row c tile (halves)
    const int ra0 = l15 * 256 + quad * 8;          // rows 0..15, + ks*32
    const int ra1 = (16 + l15) * 256 + quad * 8;   // rows 16..31

    // sB swizzle: physical slot `lane` holds logical slot s' = lane^((lane>>3)&7)
    const int spw = lane ^ ((lane >> 3) & 7);
    const int ddw = spw >> 2;          // d within 16-block
    const int jjw = spw & 3;           // j-octet within 32-j tile

    auto stageTile = [&](int it, int buf) {
        const int jb = jb0 + it * 32;
        const long tbase = (long)b * 1048576 + jb;
#pragma unroll
        for (int t = 0; t < 4; ++t) {
            const int W = wv * 4 + t;              // d-block 0..15
            async_lds16(cfT + tbase + (long)(W * 16 + ddw) * 4096 + jjw * 8,
                        &sB[buf][W * 512]);
        }
    };

    // PV read: logical slot s = 4*l15 + quad at physical p = s ^ ((s>>3)&7)
    const int pvs   = 4 * l15 + quad;
    const int pvoff = (pvs ^ ((pvs >> 3) & 7)) * 8;   // halves within 512-slot row

    // prologue: preload tile-0 ks0 A-pair (global), then stage sB(0)
    V16h pA0, pA1;
    pA0.v = *(const int4*)(cf + cb0 + ra0);
    pA1.v = *(const int4*)(cf + cb0 + ra1);
    stageTile(0, 0);

    for (int it = 0; it < jtiles; ++it) {
        const int cur = it & 1;
        const int jb  = jb0 + it * 32;
        const _Float16* cq = cf + cb0 + (long)it * 8192;   // 32 rows * 256 halves

        // Single barrier: implicit vmcnt(0) drains OWN sB DMA (issued one
        // phase ago); barrier => sB[cur] resident AND all waves done with
        // sB[cur^1].
        __syncthreads();

        // ---- S^T = c (A direct from global, 2-deep pipeline) . q^T ----
        floatx4 accS0 = (floatx4)(0.0f), accS1 = (floatx4)(0.0f);
        V16h a0c = pA0, a1c = pA1;
        __builtin_amdgcn_s_setprio(1);
#pragma unroll
        for (int ks = 0; ks < 8; ++ks) {
            V16h a0n, a1n;
            if (ks < 7) {
                a0n.v = *(const int4*)(cq + ra0 + (ks + 1) * 32);
                a1n.v = *(const int4*)(cq + ra1 + (ks + 1) * 32);
            } else if (it + 1 < jtiles) {          // next tile's ks0 preload
                a0n.v = *(const int4*)(cq + 8192 + ra0);
                a1n.v = *(const int4*)(cq + 8192 + ra1);
            } else { a0n = a0c; a1n = a1c; }
            accS0 = __builtin_amdgcn_mfma_f32_16x16x32_f16(a0c.h8, qfr[ks].h8, accS0, 0, 0, 0);
            accS1 = __builtin_amdgcn_mfma_f32_16x16x32_f16(a1c.h8, qfr[ks].h8, accS1, 0, 0, 0);
            a0c = a0n; a1c = a1n;
        }
        __builtin_amdgcn_s_setprio(0);
        pA0 = a0c; pA1 = a1c;                      // next tile's ks0

        // mask + labels for THIS tile (issued before the DMA so their waits
        // leave the DMA in flight).
        const float4 mv0 = *(const float4*)(maskp + (long)b * WNC + jb + quad * 4);
        const float4 mv1 = *(const float4*)(maskp + (long)b * WNC + jb + 16 + quad * 4);
        const int4   lb0 = *(const int4*)(labels + (long)b * WNC + jb + quad * 8);
        const int4   lb1 = *(const int4*)(labels + (long)b * WNC + jb + quad * 8 + 4);
        asm volatile("" ::: "memory");   // pin: ml loads above, DMA below

        if (it + 1 < jtiles) stageTile(it + 1, cur ^ 1);

        const float* mv0p = (const float*)&mv0;
        const float* mv1p = (const float*)&mv1;
#pragma unroll
        for (int r = 0; r < 4; ++r) {
            accS0[r] *= mv0p[r];
            accS1[r] *= mv1p[r];
        }

        // ---- online max per q = lane&15 ----
        float v = fmaxf(fmaxf(fmaxf(accS0[0], accS0[1]), fmaxf(accS0[2], accS0[3])),
                        fmaxf(fmaxf(accS1[0], accS1[1]), fmaxf(accS1[2], accS1[3])));
        v = fmaxf(v, __shfl_xor(v, 16, 64));
        v = fmaxf(v, __shfl_xor(v, 32, 64));
        const float m_new = fmaxf(m_run, v);
        const bool upd = __any(m_new > m_run);
        const float alpha = __expf(m_run - m_new);
        float p[8];
#pragma unroll
        for (int r = 0; r < 4; ++r) {
            p[r]     = __expf(accS0[r] - m_new);
            p[4 + r] = __expf(accS1[r] - m_new);
        }
        m_run = m_new;

        if (upd) {
            float ar[4];
#pragma unroll
            for (int r = 0; r < 4; ++r) ar[r] = __shfl(alpha, quad * 4 + r, 64);
#pragma unroll
            for (int fo = 0; fo < 18; ++fo)
#pragma unroll
                for (int r = 0; r < 4; ++r) O[fo][r] *= ar[r];
        }

        // ---- P -> per-wave LDS (A layout [q][j]) ----
#pragma unroll
        for (int jf = 0; jf < 2; ++jf) {
            H4 w;
#pragma unroll
            for (int r = 0; r < 4; ++r) w.h[r] = (_Float16)p[jf * 4 + r];
            *(uint2*)&Pw[wv][l15 * 40 + jf * 16 + quad * 4] = w.u;
        }
        asm volatile("" ::: "memory");
        V16h pf;
        pf.v = *(const int4*)&Pw[wv][l15 * 40 + quad * 8];

        const int* lbp0 = (const int*)&lb0;
        const int* lbp1 = (const int*)&lb1;
        V16h oh0, oh1;
#pragma unroll
        for (int i = 0; i < 8; ++i) {
            const int lv = (i < 4) ? lbp0[i] : lbp1[i - 4];
            oh0.h[i] = (lv == l15)        ? (_Float16)1.0f : (_Float16)0.0f;
            // col 31 (l15==15): all-ones column accumulates l in O[17]
            oh1.h[i] = (lv == (l15 + 16) || l15 == 15) ? (_Float16)1.0f : (_Float16)0.0f;
        }

        // ---- O += P @ [c | onehot+ones] (B from sB, swizzled slots) ----
        __builtin_amdgcn_s_setprio(1);
#pragma unroll
        for (int dt = 0; dt < 16; ++dt) {
            V16h bfr;
            bfr.v = *(const int4*)&sB[cur][dt * 512 + pvoff];
            O[dt] = __builtin_amdgcn_mfma_f32_16x16x32_f16(pf.h8, bfr.h8, O[dt], 0, 0, 0);
        }
        O[16] = __builtin_amdgcn_mfma_f32_16x16x32_f16(pf.h8, oh0.h8, O[16], 0, 0, 0);
        O[17] = __builtin_amdgcn_mfma_f32_16x16x32_f16(pf.h8, oh1.h8, O[17], 0, 0, 0);
        __builtin_amdgcn_s_setprio(0);
    }

    {
        const long base = (long)(sp * WB + b) * WNQ + q0 + wv * 16;
#pragma unroll
        for (int dt = 0; dt < 18; ++dt)
#pragma unroll
            for (int r = 0; r < 4; ++r) {
                H4 h; h.h[0] = (_Float16)O[dt][r];
                Oh[(base + quad * 4 + r) * 288 + dt * 16 + l15] = h.s[0];
            }
        if (lane < 16) Mst[base + lane] = m_run;
        if (l15 == 15) {
#pragma unroll
            for (int r = 0; r < 4; ++r)
                Lst[base + quad * 4 + r] = O[17][r];   // ones-column = l
        }
    }
}

// ---------------------------------------------------------------------------
// Combine splits + log_softmax(gen) + gate + logaddexp. 4 rows per block.
// ---------------------------------------------------------------------------
__global__ __launch_bounds__(256) void final_kernel(
    const float* __restrict__ genlog,
    const unsigned short* __restrict__ Oh,
    const float* __restrict__ Mst,
    const float* __restrict__ Lst,
    const float* __restrict__ Wcp,
    const float* __restrict__ bcp,
    float* __restrict__ outp,
    int ns)
{
    __shared__ float gA[4][32];
    __shared__ float cdA[4][32];

    const int tid  = threadIdx.x;
    const int lane = tid & 63;
    const int wv   = tid >> 6;
    const int row  = blockIdx.x * 4 + wv;

    float ms[8];
#pragma unroll
    for (int s = 0; s < 8; ++s) ms[s] = (s < ns) ? Mst[(long)s * NROWS + row] : -INFINITY;
    float mstar = -INFINITY;
#pragma unroll
    for (int s = 0; s < 8; ++s) mstar = fmaxf(mstar, ms[s]);
    float wgt[8]; float L = 0.f;
#pragma unroll
    for (int s = 0; s < 8; ++s) {
        wgt[s] = (ms[s] == -INFINITY) ? 0.f : __expf(ms[s] - mstar);
        if (s < ns) L += Lst[(long)s * NROWS + row] * wgt[s];
    }

    const int d0 = lane * 4;
    float ctx[4] = {0.f, 0.f, 0.f, 0.f};
#pragma unroll
    for (int s = 0; s < 8; ++s) {
        if (s < ns) {
            H4 t; t.u = *(const uint2*)&Oh[((long)s * NROWS + row) * 288 + d0];
#pragma unroll
            for (int i = 0; i < 4; ++i) ctx[i] += wgt[s] * (float)t.h[i];
        }
    }

    float cls[4] = {0.f, 0.f, 0.f, 0.f};
    if (lane < 8) {
#pragma unroll
        for (int s = 0; s < 8; ++s) {
            if (s < ns) {
                H4 t; t.u = *(const uint2*)&Oh[((long)s * NROWS + row) * 288 + 256 + lane * 4];
#pragma unroll
                for (int i = 0; i < 4; ++i) cls[i] += wgt[s] * (float)t.h[i];
            }
        }
    }

    float g = (lane < 25) ? genlog[(long)row * 32 + lane] : -INFINITY;
    float mg = g;
#pragma unroll
    for (int off = 32; off >= 1; off >>= 1) mg = fmaxf(mg, __shfl_xor(mg, off, 64));
    float se = (lane < 25) ? __expf(g - mg) : 0.f;
#pragma unroll
    for (int off = 32; off >= 1; off >>= 1) se += __shfl_xor(se, off, 64);
    const float glsm = g - mg - logf(se);

    const float qgate = genlog[(long)row * 32 + 25];
    const float invL = 1.f / L;
    float part = 0.f;
#pragma unroll
    for (int i = 0; i < 4; ++i)
        part += ctx[i] * invL * Wcp[256 + d0 + i];
#pragma unroll
    for (int off = 32; off >= 1; off >>= 1) part += __shfl_xor(part, off, 64);
    const float logit = qgate + part + bcp[0];

    const float lscp  = logsig(logit);
    const float lsgen = logsig(-logit);
    const float logL  = logf(L);

    if (lane < 8) {
#pragma unroll
        for (int i = 0; i < 4; ++i)
            cdA[wv][lane * 4 + i] = (cls[i] > 0.f) ? (logf(cls[i]) - logL) : -INFINITY;
    }
    if (lane < 25) gA[wv][lane] = glsm;
    __syncthreads();

    if (lane < 25) {
        const float a  = lscp + cdA[wv][lane];
        const float bb = lsgen + gA[wv][lane];
        const float mx = fmaxf(a, bb);
        const float o  = (mx == -INFINITY) ? -INFINITY
                         : mx + log1pf(__expf(fminf(a, bb) - mx));
        outp[(long)row * 25 + lane] = o;
    }
}

// ---------------------------------------------------------------------------
extern "C" void kernel_launch(void* const* d_in, const int* in_sizes, int n_in,
                              void* d_out, int out_size, void* d_ws, size_t ws_size,
                              hipStream_t stream) {
    const float* q_head = (const float*)d_in[0];
    const float* q_tail = (const float*)d_in[1];
    const float* c_head = (const float*)d_in[2];
    const float* c_tail = (const float*)d_in[3];
    const int*   labels = (const int*)d_in[4];
    const float* maskp  = (const float*)d_in[5];
    const float* Wrel   = (const float*)d_in[6];
    const float* brel   = (const float*)d_in[7];
    const float* Wgen   = (const float*)d_in[8];
    const float* bgen   = (const float*)d_in[9];
    const float* Wcp    = (const float*)d_in[10];
    const float* bcp    = (const float*)d_in[11];

    auto need = [](long ns) -> long { return 39075840l + ns * 4784128l; };
    int ns = 8, nsh = 3;                       // 1024 blocks -> 3+/CU (R10 decode)
    if ((long)ws_size < need(8)) { ns = 4; nsh = 2; }
    if ((long)ws_size < need(4)) { ns = 2; nsh = 1; }
    if ((long)ws_size < need(2)) { ns = 1; nsh = 0; }
    const int jtiles = 128 / ns;

    char* ws = (char*)d_ws;
    _Float16* Qf     = (_Float16*)(ws);                   //  4 MB
    _Float16* Cf     = (_Float16*)(ws + 4194304l);        // 16 MB
    _Float16* CfT    = (_Float16*)(ws + 20971520l);       // 16 MB
    _Float16* WT     = (_Float16*)(ws + 37748736l);       // 256 KB
    _Float16* GenB   = (_Float16*)(ws + 38010880l);       // 16 KB
    float*    genlog = (float*)   (ws + 38027264l);       //  1 MB
    unsigned short* Oh = (unsigned short*)(ws + 39075840l);  // ns*4.5 MB fp16
    float*    Mst    = (float*)   (ws + 39075840l + (long)ns * 4718592l);
    float*    Lst    = Mst + (long)ns * NROWS;

    hipLaunchKernelGGL(wprep_kernel, dim3(288), dim3(256), 0, stream,
                       Wrel, Wgen, Wcp, WT, GenB);
    hipLaunchKernelGGL(emb_kernel, dim3(640), dim3(256), 0, stream,
                       q_head, q_tail, c_head, c_tail, WT, brel, GenB, bgen,
                       Qf, Cf, CfT, genlog);
    hipLaunchKernelGGL(attn_kernel, dim3(16 * 8 * ns), dim3(256), 0, stream,
                       Qf, Cf, CfT, labels, maskp, Oh, Mst, Lst, jtiles, nsh);
    hipLaunchKernelGGL(final_kernel, dim3(NROWS / 4), dim3(256), 0, stream,
                       genlog, Oh, Mst, Lst, Wcp, bcp, (float*)d_out, ns);
}

// Round 13
// 334.146 us; speedup vs baseline: 1.2056x; 1.2056x over previous
//
#include <hip/hip_runtime.h>

// B=8, NQ=1024, NC=4096, D=256, C+1=25. FP32 I/O; labels int32.
// R21: attn occupancy fix with proven ingredients. R20 (QK direct-from-
// global) failed: serial load->MFMA dependence, 235us. R21 keeps R19's
// DMA->LDS->MFMA form but SINGLE-buffers sA: LDS 69->53.25KB -> 3 blk/CU
// (12 waves, was 8; R19 was latency-bound, no pipe >50%). Two barriers
// per iter, both DMAs keep real slack: TOP -> ml -> fence -> sB(it+1) DMA
// -> QK(sA) -> MID(sA free; drains sB DMA w/ QK-phase slack) -> sA(it+1)
// DMA -> softmax/PV (sA DMA drained at next TOP). ns=8, grid 1024, R10-
// measured decode (b=u, sp=xcd; FETCH 33MB proven at q-tile 64/16qt).
// sA/sB layouts byte-identical to R19 (sB slot-XOR swizzle kept).
// emb/final/wprep byte-identical to R19 (best total 248.4us).

typedef __attribute__((ext_vector_type(8))) _Float16 half8;
typedef __attribute__((ext_vector_type(4))) float floatx4;

#define WB 8
#define WNQ 1024
#define WNC 4096
#define NROWS 8192          // B*NQ

static __device__ __forceinline__ float logsig(float x) {
    return (x >= 0.f) ? -log1pf(__expf(-x)) : x - log1pf(__expf(x));
}

union V16h { int4 v; half8 h8; _Float16 h[8]; unsigned short s[8]; uint2 u2[2]; };
union F8   { float4 v[2]; float f[8]; };
union H4   { _Float16 h[4]; uint2 u; unsigned short s[4]; };

static __device__ __forceinline__ void async_lds16(const _Float16* g, _Float16* l) {
    __builtin_amdgcn_global_load_lds(
        (const __attribute__((address_space(1))) unsigned int*)g,
        (__attribute__((address_space(3))) unsigned int*)l,
        16, 0, 0);
}

static __device__ __forceinline__ void async_lds16f(const float* g, float* l) {
    __builtin_amdgcn_global_load_lds(
        (const __attribute__((address_space(1))) unsigned int*)g,
        (__attribute__((address_space(3))) unsigned int*)l,
        16, 0, 0);
}

// ---------------------------------------------------------------------------
// wprep: WT fp16 [256 n][512 k] = W_rel^T; GenB fp16 [32 n][256 k].
// ---------------------------------------------------------------------------
__global__ void wprep_kernel(const float* __restrict__ Wrel,
                             const float* __restrict__ Wgen,
                             const float* __restrict__ Wcp,
                             _Float16* __restrict__ WT,
                             _Float16* __restrict__ GenB)
{
    const int bx = blockIdx.x;
    if (bx < 256) {
        const int n = bx;
        for (int k = threadIdx.x; k < 512; k += 256)
            WT[(long)n * 512 + k] = (_Float16)Wrel[(long)k * 256 + n];
    } else {
        const int n = bx - 256;
        const int k = threadIdx.x;
        float v = 0.f;
        if (n < 25)       v = Wgen[(long)k * 25 + n];
        else if (n == 25) v = Wcp[k];
        GenB[(long)n * 256 + k] = (_Float16)v;
    }
}

// ---------------------------------------------------------------------------
// emb v3 (R18/R19): concat(head,tail) @ W_rel + b_rel -> fp16. fp32 A-tile
// async-DMA'd to LDS, double-buffered, single barrier per K-step.
// ---------------------------------------------------------------------------
__global__ __launch_bounds__(256, 2) void emb_kernel(
    const float* __restrict__ q_head, const float* __restrict__ q_tail,
    const float* __restrict__ c_head, const float* __restrict__ c_tail,
    const _Float16* __restrict__ WT,
    const float* __restrict__ brel,
    const _Float16* __restrict__ GenB,
    const float* __restrict__ bgen,
    _Float16* __restrict__ Qf, _Float16* __restrict__ Cf,
    _Float16* __restrict__ CfT,
    float* __restrict__ genlog)
{
    __shared__ float sA32[2][2048];    // 16 KB dbuf fp32 A-tile [64r][32k] chunk-swizzled
    __shared__ _Float16 sO[64 * 264];  // 33 KB: q natural [m][264] / c swizzled

    const int tid  = threadIdx.x;
    const int lane = tid & 63;
    const int wv   = tid >> 6;
    const int l15  = lane & 15;
    const int quad = lane >> 4;
    const int n0   = wv * 64;

    const float* head; const float* tail; _Float16* Ef;
    long m0; bool isQ;
    if (blockIdx.x < 128) {
        isQ = true;  head = q_head; tail = q_tail; Ef = Qf;
        m0 = (long)blockIdx.x * 64;
    } else {
        isQ = false; head = c_head; tail = c_tail; Ef = Cf;
        m0 = (long)(blockIdx.x - 128) * 64;
    }

    const int srow = wv * 8 + (lane >> 3);   // row within 32-row half-tile
    const int sch  = lane & 7;               // physical chunk slot

    auto stageA = [&](int kg, int buf) {
        const float* srcb = (kg < 256) ? (head + kg) : (tail + (kg - 256));
#pragma unroll
        for (int t = 0; t < 2; ++t) {
            const int r = t * 32 + srow;                       // tile row 0..63
            const int colsw = ((sch ^ (r & 7)) << 2);          // swizzled chunk *4 floats
            async_lds16f(srcb + (m0 + r) * 256 + colsw,
                         &sA32[buf][t * 1024 + wv * 256]);     // wave-uniform base
        }
    };

    floatx4 acc[4][4];
#pragma unroll
    for (int a = 0; a < 4; ++a)
#pragma unroll
        for (int bq = 0; bq < 4; ++bq) acc[a][bq] = (floatx4)(0.0f);

    V16h wCur[4];
#pragma unroll
    for (int nt = 0; nt < 4; ++nt)
        wCur[nt].v = *(const int4*)(WT + (long)(n0 + nt * 16 + l15) * 512 + quad * 8);

    stageA(0, 0);                       // prologue prefetch into buf 0

    for (int ks = 0; ks < 16; ++ks) {
        const int cur = ks & 1;
        __syncthreads();                // drains own DMA (issued last iter) + readers

        V16h wNxt[4];
        if (ks < 15) {
            const int kg = (ks + 1) * 32;
            stageA(kg, cur ^ 1);
#pragma unroll
            for (int nt = 0; nt < 4; ++nt)
                wNxt[nt].v = *(const int4*)(WT + (long)(n0 + nt * 16 + l15) * 512 + kg + quad * 8);
        } else {
#pragma unroll
            for (int nt = 0; nt < 4; ++nt) wNxt[nt] = wCur[nt];
        }

        V16h af[4];
#pragma unroll
        for (int mb = 0; mb < 4; ++mb) {
            const int row  = mb * 16 + l15;
            const int base = row * 32;
            const int p0   = ((quad * 2)     ^ (row & 7)) * 4;
            const int p1   = ((quad * 2 + 1) ^ (row & 7)) * 4;
            const float4 f0 = *(const float4*)&sA32[cur][base + p0];
            const float4 f1 = *(const float4*)&sA32[cur][base + p1];
            af[mb].h[0] = (_Float16)f0.x; af[mb].h[1] = (_Float16)f0.y;
            af[mb].h[2] = (_Float16)f0.z; af[mb].h[3] = (_Float16)f0.w;
            af[mb].h[4] = (_Float16)f1.x; af[mb].h[5] = (_Float16)f1.y;
            af[mb].h[6] = (_Float16)f1.z; af[mb].h[7] = (_Float16)f1.w;
        }
#pragma unroll
        for (int mb = 0; mb < 4; ++mb)
#pragma unroll
            for (int nt = 0; nt < 4; ++nt)
                acc[mb][nt] = __builtin_amdgcn_mfma_f32_16x16x32_f16(af[mb].h8, wCur[nt].h8, acc[mb][nt], 0, 0, 0);

#pragma unroll
        for (int nt = 0; nt < 4; ++nt) wCur[nt] = wNxt[nt];
    }

    float bias[4];
#pragma unroll
    for (int nt = 0; nt < 4; ++nt) bias[nt] = brel[n0 + nt * 16 + l15];

#pragma unroll
    for (int mb = 0; mb < 4; ++mb)
#pragma unroll
        for (int nt = 0; nt < 4; ++nt) {
            H4 hq;
#pragma unroll
            for (int r = 0; r < 4; ++r) {
                const long row = m0 + mb * 16 + quad * 4 + r;
                const _Float16 h = (_Float16)(acc[mb][nt][r] + bias[nt]);
                Ef[row * 256 + n0 + nt * 16 + l15] = h;
                hq.h[r] = h;
                if (isQ)   // natural tile for fused gen head
                    sO[(mb * 16 + quad * 4 + r) * 264 + n0 + nt * 16 + l15] = h;
            }
            if (!isQ) {
                const int n  = n0 + nt * 16 + l15;
                const int sw = (mb * 4 + quad) ^ l15;
                *(uint2*)&sO[n * 64 + sw * 4] = hq.u;
            }
        }

    __syncthreads();
    if (isQ) {
        // ---- fused gen head: genlog[m][32] = q_emb @ GenB^T (+bgen) ----
        floatx4 ga[2];
        ga[0] = (floatx4)(0.0f); ga[1] = (floatx4)(0.0f);
#pragma unroll
        for (int ks = 0; ks < 8; ++ks) {
            V16h a, b0, b1;
            a.v  = *(const int4*)&sO[(wv * 16 + l15) * 264 + ks * 32 + quad * 8];
            b0.v = *(const int4*)(GenB + (long)(l15)      * 256 + ks * 32 + quad * 8);
            b1.v = *(const int4*)(GenB + (long)(16 + l15) * 256 + ks * 32 + quad * 8);
            ga[0] = __builtin_amdgcn_mfma_f32_16x16x32_f16(a.h8, b0.h8, ga[0], 0, 0, 0);
            ga[1] = __builtin_amdgcn_mfma_f32_16x16x32_f16(a.h8, b1.h8, ga[1], 0, 0, 0);
        }
#pragma unroll
        for (int nt = 0; nt < 2; ++nt) {
            const int col = nt * 16 + l15;
            const float bb = (col < 25) ? bgen[col] : 0.f;
#pragma unroll
            for (int r = 0; r < 4; ++r)
                genlog[(m0 + wv * 16 + quad * 4 + r) * 32 + col] = ga[nt][r] + bb;
        }
    } else {
        const int bidx = (int)(m0 >> 12);
        const int jc0  = (int)(m0 & 4095);
        const int c    = tid & 7;
        const int nl   = tid >> 3;
#pragma unroll
        for (int i = 0; i < 8; ++i) {
            const int n  = nl + 32 * i;
            const int s0 = (2 * c)     ^ (n & 15);
            const int s1 = (2 * c + 1) ^ (n & 15);
            const uint2 u0 = *(const uint2*)&sO[n * 64 + s0 * 4];
            const uint2 u1 = *(const uint2*)&sO[n * 64 + s1 * 4];
            int4 out; out.x = u0.x; out.y = u0.y; out.z = u1.x; out.w = u1.y;
            *(int4*)&CfT[(long)bidx * 1048576 + (long)n * 4096 + jc0 + c * 8] = out;
        }
    }
}

// ---------------------------------------------------------------------------
// Fused flash attention + grouped class sums. 256 thr, q-tile 64, j-tile 32.
// grid 16qt*8b*8ns = 1024 (R10-measured decode: b=u, sp=xcd, FETCH 33MB).
// LDS 53.25KB: sA SINGLE-buffered (16KB) + sB dbuf (32KB, slot-swizzled)
// + Pw (5KB) -> 3 blocks/CU. Two barriers/iter, both DMAs keep slack:
// TOP -> ml -> sB(it+1) DMA -> QK(sA) -> MID -> sA(it+1) DMA -> sm/PV.
// l via ones-column MFMA (B col 31 == 1 -> O[17] accumulates row sums).
// ---------------------------------------------------------------------------
__global__ __launch_bounds__(256, 3) void attn_kernel(
    const _Float16* __restrict__ qf,
    const _Float16* __restrict__ cf,
    const _Float16* __restrict__ cfT,
    const int*      __restrict__ labels,
    const float*    __restrict__ maskp,
    unsigned short* __restrict__ Oh,    // fp16 [ns*8192][288]
    float* __restrict__ Mst,
    float* __restrict__ Lst,
    int jtiles, int nsh)
{
    __shared__ _Float16 sA[8192];       // 16 KB single-buffered natural c tile
    __shared__ _Float16 sB[2][8192];    // 32 KB dbuf transposed c tile (slot-swizzled)
    __shared__ _Float16 Pw[4][16 * 40]; //  5 KB per-wave P

    const int tid  = threadIdx.x;
    const int lane = tid & 63;
    const int wv   = tid >> 6;
    const int l15  = lane & 15;
    const int quad = lane >> 4;

    const int f   = blockIdx.x;
    const int xcd = f & 7;
    const int seq = f >> 3;
    const int qt  = seq & 15;
    const int u   = seq >> 4;
    const int pr  = u * 8 + xcd;
    const int b   = pr >> nsh;
    const int sp  = pr & ((1 << nsh) - 1);
    const int q0  = qt * 64;

    V16h qfr[8];
    {
        const long qrow = (long)b * WNQ + q0 + wv * 16 + l15;
#pragma unroll
        for (int ks = 0; ks < 8; ++ks)
            qfr[ks].v = *(const int4*)(qf + qrow * 256 + ks * 32 + quad * 8);
    }

    floatx4 O[18];
#pragma unroll
    for (int i = 0; i < 18; ++i) O[i] = (floatx4)(0.0f);
    float m_run = -INFINITY;

    const int jb0 = sp * (jtiles * 32);

    auto stageAfn = [&](int it) {
        const int jb = jb0 + it * 32;
        const long cbase = ((long)b * WNC + jb) * 256;
#pragma unroll
        for (int t = 0; t < 4; ++t) {
            const int idx = wv * 4 + t;            // 0..15
            const int ks = idx >> 1, jh = idx & 1;
            async_lds16(cf + cbase + (jh * 16 + l15) * 256 + ks * 32 + quad * 8,
                        &sA[idx * 512]);
        }
    };

    // sB swizzle: physical slot `lane` holds logical slot s' = lane^((lane>>3)&7)
    const int spw = lane ^ ((lane >> 3) & 7);
    const int ddw = spw >> 2;          // d within 16-block
    const int jjw = spw & 3;           // j-octet within 32-j tile

    auto stageBfn = [&](int it, int buf) {
        const int jb = jb0 + it * 32;
        const long tbase = (long)b * 1048576 + jb;
#pragma unroll
        for (int t = 0; t < 4; ++t) {
            const int W = wv * 4 + t;              // d-block 0..15
            async_lds16(cfT + tbase + (long)(W * 16 + ddw) * 4096 + jjw * 8,
                        &sB[buf][W * 512]);
        }
    };

    // PV read: logical slot s = 4*l15 + quad at physical p = s ^ ((s>>3)&7)
    const int pvs   = 4 * l15 + quad;
    const int pvoff = (pvs ^ ((pvs >> 3) & 7)) * 8;   // halves within 512-slot row

    stageAfn(0);                        // prologue: both tile-0 DMAs
    stageBfn(0, 0);

    for (int it = 0; it < jtiles; ++it) {
        const int cur = it & 1;
        const int jb  = jb0 + it * 32;

        // TOP barrier: drains sA(it) DMA (issued after prev MID / prologue)
        // and sB(it) DMA (issued after prev TOP / prologue); all waves done
        // reading sB[cur^1].
        __syncthreads();

        // mask + labels for THIS tile, before the sB DMA so their waits
        // leave the DMA in flight.
        const float4 mv0 = *(const float4*)(maskp + (long)b * WNC + jb + quad * 4);
        const float4 mv1 = *(const float4*)(maskp + (long)b * WNC + jb + 16 + quad * 4);
        const int4   lb0 = *(const int4*)(labels + (long)b * WNC + jb + quad * 8);
        const int4   lb1 = *(const int4*)(labels + (long)b * WNC + jb + quad * 8 + 4);
        asm volatile("" ::: "memory");   // pin: ml loads above, DMA below

        if (it + 1 < jtiles) stageBfn(it + 1, cur ^ 1);

        // ---- S^T = c (A from sA) . q^T (B regs) ----
        floatx4 accS0 = (floatx4)(0.0f), accS1 = (floatx4)(0.0f);
        __builtin_amdgcn_s_setprio(1);
#pragma unroll
        for (int ks = 0; ks < 8; ++ks) {
            V16h a0, a1;
            a0.v = *(const int4*)&sA[(ks * 2 + 0) * 512 + (quad * 16 + l15) * 8];
            a1.v = *(const int4*)&sA[(ks * 2 + 1) * 512 + (quad * 16 + l15) * 8];
            accS0 = __builtin_amdgcn_mfma_f32_16x16x32_f16(a0.h8, qfr[ks].h8, accS0, 0, 0, 0);
            accS1 = __builtin_amdgcn_mfma_f32_16x16x32_f16(a1.h8, qfr[ks].h8, accS1, 0, 0, 0);
        }
        __builtin_amdgcn_s_setprio(0);

        // MID barrier: all waves done reading sA -> safe to overwrite.
        // (Drains the sB(it+1) DMA with QK-phase slack — L2-resident src.)
        __syncthreads();
        if (it + 1 < jtiles) stageAfn(it + 1);   // lands during sm/PV

        const float* mv0p = (const float*)&mv0;
        const float* mv1p = (const float*)&mv1;
#pragma unroll
        for (int r = 0; r < 4; ++r) {
            accS0[r] *= mv0p[r];
            accS1[r] *= mv1p[r];
        }

        // ---- online max per q = lane&15 ----
        float v = fmaxf(fmaxf(fmaxf(accS0[0], accS0[1]), fmaxf(accS0[2], accS0[3])),
                        fmaxf(fmaxf(accS1[0], accS1[1]), fmaxf(accS1[2], accS1[3])));
        v = fmaxf(v, __shfl_xor(v, 16, 64));
        v = fmaxf(v, __shfl_xor(v, 32, 64));
        const float m_new = fmaxf(m_run, v);
        const bool upd = __any(m_new > m_run);
        const float alpha = __expf(m_run - m_new);
        float p[8];
#pragma unroll
        for (int r = 0; r < 4; ++r) {
            p[r]     = __expf(accS0[r] - m_new);
            p[4 + r] = __expf(accS1[r] - m_new);
        }
        m_run = m_new;

        if (upd) {
            float ar[4];
#pragma unroll
            for (int r = 0; r < 4; ++r) ar[r] = __shfl(alpha, quad * 4 + r, 64);
#pragma unroll
            for (int fo = 0; fo < 18; ++fo)
#pragma unroll
                for (int r = 0; r < 4; ++r) O[fo][r] *= ar[r];
        }

        // ---- P -> per-wave LDS (A layout [q][j]) ----
#pragma unroll
        for (int jf = 0; jf < 2; ++jf) {
            H4 w;
#pragma unroll
            for (int r = 0; r < 4; ++r) w.h[r] = (_Float16)p[jf * 4 + r];
            *(uint2*)&Pw[wv][l15 * 40 + jf * 16 + quad * 4] = w.u;
        }
        asm volatile("" ::: "memory");
        V16h pf;
        pf.v = *(const int4*)&Pw[wv][l15 * 40 + quad * 8];

        const int* lbp0 = (const int*)&lb0;
        const int* lbp1 = (const int*)&lb1;
        V16h oh0, oh1;
#pragma unroll
        for (int i = 0; i < 8; ++i) {
            const int lv = (i < 4) ? lbp0[i] : lbp1[i - 4];
            oh0.h[i] = (lv == l15)        ? (_Float16)1.0f : (_Float16)0.0f;
            // col 31 (l15==15): all-ones column accumulates l in O[17]
            oh1.h[i] = (lv == (l15 + 16) || l15 == 15) ? (_Float16)1.0f : (_Float16)0.0f;
        }

        // ---- O += P @ [c | onehot+ones] (B from sB[cur], swizzled slots) ----
        __builtin_amdgcn_s_setprio(1);
#pragma unroll
        for (int dt = 0; dt < 16; ++dt) {
            V16h bfr;
            bfr.v = *(const int4*)&sB[cur][dt * 512 + pvoff];
            O[dt] = __builtin_amdgcn_mfma_f32_16x16x32_f16(pf.h8, bfr.h8, O[dt], 0, 0, 0);
        }
        O[16] = __builtin_amdgcn_mfma_f32_16x16x32_f16(pf.h8, oh0.h8, O[16], 0, 0, 0);
        O[17] = __builtin_amdgcn_mfma_f32_16x16x32_f16(pf.h8, oh1.h8, O[17], 0, 0, 0);
        __builtin_amdgcn_s_setprio(0);
    }

    {
        const long base = (long)(sp * WB + b) * WNQ + q0 + wv * 16;
#pragma unroll
        for (int dt = 0; dt < 18; ++dt)
#pragma unroll
            for (int r = 0; r < 4; ++r) {
                H4 h; h.h[0] = (_Float16)O[dt][r];
                Oh[(base + quad * 4 + r) * 288 + dt * 16 + l15] = h.s[0];
            }
        if (lane < 16) Mst[base + lane] = m_run;
        if (l15 == 15) {
#pragma unroll
            for (int r = 0; r < 4; ++r)
                Lst[base + quad * 4 + r] = O[17][r];   // ones-column = l
        }
    }
}

// ---------------------------------------------------------------------------
// Combine splits + log_softmax(gen) + gate + logaddexp. 4 rows per block.
// ---------------------------------------------------------------------------
__global__ __launch_bounds__(256) void final_kernel(
    const float* __restrict__ genlog,
    const unsigned short* __restrict__ Oh,
    const float* __restrict__ Mst,
    const float* __restrict__ Lst,
    const float* __restrict__ Wcp,
    const float* __restrict__ bcp,
    float* __restrict__ outp,
    int ns)
{
    __shared__ float gA[4][32];
    __shared__ float cdA[4][32];

    const int tid  = threadIdx.x;
    const int lane = tid & 63;
    const int wv   = tid >> 6;
    const int row  = blockIdx.x * 4 + wv;

    float ms[8];
#pragma unroll
    for (int s = 0; s < 8; ++s) ms[s] = (s < ns) ? Mst[(long)s * NROWS + row] : -INFINITY;
    float mstar = -INFINITY;
#pragma unroll
    for (int s = 0; s < 8; ++s) mstar = fmaxf(mstar, ms[s]);
    float wgt[8]; float L = 0.f;
#pragma unroll
    for (int s = 0; s < 8; ++s) {
        wgt[s] = (ms[s] == -INFINITY) ? 0.f : __expf(ms[s] - mstar);
        if (s < ns) L += Lst[(long)s * NROWS + row] * wgt[s];
    }

    const int d0 = lane * 4;
    float ctx[4] = {0.f, 0.f, 0.f, 0.f};
#pragma unroll
    for (int s = 0; s < 8; ++s) {
        if (s < ns) {
            H4 t; t.u = *(const uint2*)&Oh[((long)s * NROWS + row) * 288 + d0];
#pragma unroll
            for (int i = 0; i < 4; ++i) ctx[i] += wgt[s] * (float)t.h[i];
        }
    }

    float cls[4] = {0.f, 0.f, 0.f, 0.f};
    if (lane < 8) {
#pragma unroll
        for (int s = 0; s < 8; ++s) {
            if (s < ns) {
                H4 t; t.u = *(const uint2*)&Oh[((long)s * NROWS + row) * 288 + 256 + lane * 4];
#pragma unroll
                for (int i = 0; i < 4; ++i) cls[i] += wgt[s] * (float)t.h[i];
            }
        }
    }

    float g = (lane < 25) ? genlog[(long)row * 32 + lane] : -INFINITY;
    float mg = g;
#pragma unroll
    for (int off = 32; off >= 1; off >>= 1) mg = fmaxf(mg, __shfl_xor(mg, off, 64));
    float se = (lane < 25) ? __expf(g - mg) : 0.f;
#pragma unroll
    for (int off = 32; off >= 1; off >>= 1) se += __shfl_xor(se, off, 64);
    const float glsm = g - mg - logf(se);

    const float qgate = genlog[(long)row * 32 + 25];
    const float invL = 1.f / L;
    float part = 0.f;
#pragma unroll
    for (int i = 0; i < 4; ++i)
        part += ctx[i] * invL * Wcp[256 + d0 + i];
#pragma unroll
    for (int off = 32; off >= 1; off >>= 1) part += __shfl_xor(part, off, 64);
    const float logit = qgate + part + bcp[0];

    const float lscp  = logsig(logit);
    const float lsgen = logsig(-logit);
    const float logL  = logf(L);

    if (lane < 8) {
#pragma unroll
        for (int i = 0; i < 4; ++i)
            cdA[wv][lane * 4 + i] = (cls[i] > 0.f) ? (logf(cls[i]) - logL) : -INFINITY;
    }
    if (lane < 25) gA[wv][lane] = glsm;
    __syncthreads();

    if (lane < 25) {
        const float a  = lscp + cdA[wv][lane];
        const float bb = lsgen + gA[wv][lane];
        const float mx = fmaxf(a, bb);
        const float o  = (mx == -INFINITY) ? -INFINITY
                         : mx + log1pf(__expf(fminf(a, bb) - mx));
        outp[(long)row * 25 + lane] = o;
    }
}

// ---------------------------------------------------------------------------
extern "C" void kernel_launch(void* const* d_in, const int* in_sizes, int n_in,
                              void* d_out, int out_size, void* d_ws, size_t ws_size,
                              hipStream_t stream) {
    const float* q_head = (const float*)d_in[0];
    const float* q_tail = (const float*)d_in[1];
    const float* c_head = (const float*)d_in[2];
    const float* c_tail = (const float*)d_in[3];
    const int*   labels = (const int*)d_in[4];
    const float* maskp  = (const float*)d_in[5];
    const float* Wrel   = (const float*)d_in[6];
    const float* brel   = (const float*)d_in[7];
    const float* Wgen   = (const float*)d_in[8];
    const float* bgen   = (const float*)d_in[9];
    const float* Wcp    = (const float*)d_in[10];
    const float* bcp    = (const float*)d_in[11];

    auto need = [](long ns) -> long { return 39075840l + ns * 4784128l; };
    int ns = 8, nsh = 3;                       // grid 1024, R10-measured decode
    if ((long)ws_size < need(8)) { ns = 4; nsh = 2; }
    if ((long)ws_size < need(4)) { ns = 2; nsh = 1; }
    if ((long)ws_size < need(2)) { ns = 1; nsh = 0; }
    const int jtiles = 128 / ns;

    char* ws = (char*)d_ws;
    _Float16* Qf     = (_Float16*)(ws);                   //  4 MB
    _Float16* Cf     = (_Float16*)(ws + 4194304l);        // 16 MB
    _Float16* CfT    = (_Float16*)(ws + 20971520l);       // 16 MB
    _Float16* WT     = (_Float16*)(ws + 37748736l);       // 256 KB
    _Float16* GenB   = (_Float16*)(ws + 38010880l);       // 16 KB
    float*    genlog = (float*)   (ws + 38027264l);       //  1 MB
    unsigned short* Oh = (unsigned short*)(ws + 39075840l);  // ns*4.5 MB fp16
    float*    Mst    = (float*)   (ws + 39075840l + (long)ns * 4718592l);
    float*    Lst    = Mst + (long)ns * NROWS;

    hipLaunchKernelGGL(wprep_kernel, dim3(288), dim3(256), 0, stream,
                       Wrel, Wgen, Wcp, WT, GenB);
    hipLaunchKernelGGL(emb_kernel, dim3(640), dim3(256), 0, stream,
                       q_head, q_tail, c_head, c_tail, WT, brel, GenB, bgen,
                       Qf, Cf, CfT, genlog);
    hipLaunchKernelGGL(attn_kernel, dim3(16 * 8 * ns), dim3(256), 0, stream,
                       Qf, Cf, CfT, labels, maskp, Oh, Mst, Lst, jtiles, nsh);
    hipLaunchKernelGGL(final_kernel, dim3(NROWS / 4), dim3(256), 0, stream,
                       genlog, Oh, Mst, Lst, Wcp, bcp, (float*)d_out, ns);
}